// Round 3
// baseline (1135.376 us; speedup 1.0000x reference)
//
#include <hip/hip_runtime.h>
#include <cstdint>
#include <type_traits>

typedef short bf16x8 __attribute__((ext_vector_type(8)));
typedef float f32x4 __attribute__((ext_vector_type(4)));

__device__ __forceinline__ ushort f2bf(float f) {
  union { float f; uint32_t u; } v; v.f = f;
  return (ushort)((v.u + 0x7fffu + ((v.u >> 16) & 1u)) >> 16);
}
__device__ __forceinline__ float bf2f(ushort u) {
  union { uint32_t u; float f; } v; v.u = ((uint32_t)u) << 16;
  return v.f;
}
// pack two fp32 -> two bf16
__device__ __forceinline__ uint32_t pkbf(float x, float y) {
  uint32_t ux = (__float_as_uint(x) + 0x8000u) >> 16;
  uint32_t uy = (__float_as_uint(y) + 0x8000u) & 0xffff0000u;
  return ux | uy;
}

// async global->LDS, 16B per lane; lptr must be wave-uniform
__device__ __forceinline__ void gld16(const void* g, void* l) {
  __builtin_amdgcn_global_load_lds(
      (__attribute__((address_space(1))) void*)(g),
      (__attribute__((address_space(3))) void*)(l), 16, 0, 0);
}

// load 8 K-contiguous elements as 8 bf16 packed in a uint4 (fallback path)
__device__ __forceinline__ uint4 ld8(const ushort* p) { return *(const uint4*)p; }
__device__ __forceinline__ uint4 ld8(const float* p) {
  float4 a = *(const float4*)p;
  float4 b = *(const float4*)(p + 4);
  uint4 r;
  r.x = pkbf(a.x, a.y); r.y = pkbf(a.z, a.w);
  r.z = pkbf(b.x, b.y); r.w = pkbf(b.z, b.w);
  return r;
}

// ---------------------------------------------------------------------------
// fp32 -> bf16 bulk convert: 8 elements/thread
// ---------------------------------------------------------------------------
__global__ __launch_bounds__(256) void cvt_bf16(
    const float* __restrict__ src, ushort* __restrict__ dst, int n8)
{
  int i = blockIdx.x * 256 + threadIdx.x;
  if (i >= n8) return;
  const float4* s = (const float4*)src;
  float4 a = s[2 * i], b = s[2 * i + 1];
  uint4 r;
  r.x = pkbf(a.x, a.y); r.y = pkbf(a.z, a.w);
  r.z = pkbf(b.x, b.y); r.w = pkbf(b.z, b.w);
  ((uint4*)dst)[i] = r;
}

// ---------------------------------------------------------------------------
// FAST GEMM (bf16 x bf16): C[M,N] = A[M,K] * B[N,K]^T, global_load_lds staging
// 128x128 tile, BK=32, 4 waves 2x2, 4x4 MFMA/wave.
// ---------------------------------------------------------------------------
template <bool TRANSC, typename TC>
__global__ __launch_bounds__(256) void gemm_bt_async(
    const ushort* __restrict__ A, const ushort* __restrict__ B,
    TC* __restrict__ C, int M, int N, int K, int ldc)
{
  __shared__ __align__(16) ushort As[128 * 32];
  __shared__ __align__(16) ushort Bs[128 * 32];

  const int tid  = threadIdx.x;
  const int wave = tid >> 6;
  const int lane = tid & 63;
  const int quad = lane >> 4;
  const int l16  = lane & 15;
  const int m0 = blockIdx.y * 128;
  const int n0 = blockIdx.x * 128;
  const int wm = (wave & 1) * 64;
  const int wn = (wave >> 1) * 64;

  // staging: wave w fills chunks 2w,2w+1 (16 rows each) of As and Bs.
  // lane l -> row chunkbase + (l>>2), col (l&3)*8 ; LDS dest = base + l*16B
  const int srow = lane >> 2;
  const int scol = (lane & 3) * 8;
  const ushort* ga0 = A + (size_t)(m0 + 32 * wave + srow) * K + scol;
  const ushort* ga1 = A + (size_t)(m0 + 32 * wave + 16 + srow) * K + scol;
  const ushort* gb0 = B + (size_t)(n0 + 32 * wave + srow) * K + scol;
  const ushort* gb1 = B + (size_t)(n0 + 32 * wave + 16 + srow) * K + scol;
  ushort* la0 = As + (2 * wave) * 512;
  ushort* la1 = As + (2 * wave + 1) * 512;
  ushort* lb0 = Bs + (2 * wave) * 512;
  ushort* lb1 = Bs + (2 * wave + 1) * 512;

  f32x4 acc[4][4];
#pragma unroll
  for (int i = 0; i < 4; i++)
#pragma unroll
    for (int j = 0; j < 4; j++) acc[i][j] = {0.f, 0.f, 0.f, 0.f};

  for (int k0 = 0; k0 < K; k0 += 32) {
    __syncthreads();
    gld16(ga0 + k0, la0);
    gld16(ga1 + k0, la1);
    gld16(gb0 + k0, lb0);
    gld16(gb1 + k0, lb1);
    __syncthreads();   // compiler drains vmcnt before s_barrier

    bf16x8 af[4], bfr[4];
#pragma unroll
    for (int i = 0; i < 4; i++) {
      af[i]  = *(const bf16x8*)(As + (wm + i * 16 + l16) * 32 + quad * 8);
      bfr[i] = *(const bf16x8*)(Bs + (wn + i * 16 + l16) * 32 + quad * 8);
    }
#pragma unroll
    for (int im = 0; im < 4; im++)
#pragma unroll
      for (int in = 0; in < 4; in++)
        acc[im][in] = __builtin_amdgcn_mfma_f32_16x16x32_bf16(
            af[im], bfr[in], acc[im][in], 0, 0, 0);
  }

#pragma unroll
  for (int im = 0; im < 4; im++)
#pragma unroll
    for (int in = 0; in < 4; in++)
#pragma unroll
      for (int r = 0; r < 4; r++) {
        int row = m0 + wm + im * 16 + quad * 4 + r;
        int col = n0 + wn + in * 16 + l16;
        float fv = acc[im][in][r];
        TC val;
        if constexpr (std::is_same<TC, ushort>::value) val = f2bf(fv);
        else                                           val = fv;
        if (TRANSC) C[(size_t)col * ldc + row] = val;
        else        C[(size_t)row * ldc + col] = val;
      }
}

// ---------------------------------------------------------------------------
// FALLBACK GEMM (mixed fp32/bf16 inputs, VGPR staging) -- round-1 proven
// ---------------------------------------------------------------------------
template <bool TRANSC, typename TA, typename TB, typename TC>
__global__ __launch_bounds__(256) void gemm_bt(
    const TA* __restrict__ A, const TB* __restrict__ B,
    TC* __restrict__ C, int M, int N, int K, int ldc)
{
  __shared__ __align__(16) ushort As[128 * 32];
  __shared__ __align__(16) ushort Bs[128 * 32];

  const int tid  = threadIdx.x;
  const int wave = tid >> 6;
  const int lane = tid & 63;
  const int quad = lane >> 4;
  const int l16  = lane & 15;
  const int m0 = blockIdx.y * 128;
  const int n0 = blockIdx.x * 128;
  const int wm = (wave & 1) * 64;
  const int wn = (wave >> 1) * 64;
  const int r0 = tid >> 2;
  const int c0 = (tid & 3) * 8;

  f32x4 acc[4][4];
#pragma unroll
  for (int i = 0; i < 4; i++)
#pragma unroll
    for (int j = 0; j < 4; j++) acc[i][j] = {0.f, 0.f, 0.f, 0.f};

  const TA* aptr = A + (size_t)(m0 + r0) * K + c0;
  const TB* bptr = B + (size_t)(n0 + r0) * K + c0;

  for (int k0 = 0; k0 < K; k0 += 32) {
    uint4 av0 = ld8(aptr + k0);
    uint4 av1 = ld8(aptr + (size_t)64 * K + k0);
    uint4 bv0 = ld8(bptr + k0);
    uint4 bv1 = ld8(bptr + (size_t)64 * K + k0);
    __syncthreads();
    *(uint4*)(As + r0 * 32 + c0)        = av0;
    *(uint4*)(As + (r0 + 64) * 32 + c0) = av1;
    *(uint4*)(Bs + r0 * 32 + c0)        = bv0;
    *(uint4*)(Bs + (r0 + 64) * 32 + c0) = bv1;
    __syncthreads();

    bf16x8 af[4], bfr[4];
#pragma unroll
    for (int i = 0; i < 4; i++) {
      af[i]  = *(const bf16x8*)(As + (wm + i * 16 + l16) * 32 + quad * 8);
      bfr[i] = *(const bf16x8*)(Bs + (wn + i * 16 + l16) * 32 + quad * 8);
    }
#pragma unroll
    for (int im = 0; im < 4; im++)
#pragma unroll
      for (int in = 0; in < 4; in++)
        acc[im][in] = __builtin_amdgcn_mfma_f32_16x16x32_bf16(
            af[im], bfr[in], acc[im][in], 0, 0, 0);
  }

#pragma unroll
  for (int im = 0; im < 4; im++)
#pragma unroll
    for (int in = 0; in < 4; in++)
#pragma unroll
      for (int r = 0; r < 4; r++) {
        int row = m0 + wm + im * 16 + quad * 4 + r;
        int col = n0 + wn + in * 16 + l16;
        float fv = acc[im][in][r];
        TC val;
        if constexpr (std::is_same<TC, ushort>::value) val = f2bf(fv);
        else                                           val = fv;
        if (TRANSC) C[(size_t)col * ldc + row] = val;
        else        C[(size_t)row * ldc + col] = val;
      }
}

// ---------------------------------------------------------------------------
// RoPE on K (bf16) in place
// ---------------------------------------------------------------------------
__global__ __launch_bounds__(256) void rope_kernel(ushort* __restrict__ Kb)
{
  int idx = blockIdx.x * 256 + threadIdx.x;
  int j  = idx & 63;
  int hs = idx >> 6;
  int s  = hs >> 5;
  float freq = expf(-0.14391156f * (float)j);
  float ang  = (float)s * freq;
  float sn, c;
  sincosf(ang, &sn, &c);
  size_t base = (size_t)hs * 128 + j;
  float k1 = bf2f(Kb[base]);
  float k2 = bf2f(Kb[base + 64]);
  Kb[base]      = f2bf(k1 * c - k2 * sn);
  Kb[base + 64] = f2bf(k2 * c + k1 * sn);
}

// ---------------------------------------------------------------------------
// Flash attention v2: block = 1 head x 128 q rows; wave owns 32 q (2 subtiles).
// 64-key KV tiles (Kt 16KB + Vs 16KB + Ps 16KB = 48KB LDS). K/V fragments
// reused across both q-subtiles: 36 ds_read_b128 per 64 MFMA per wave/tile.
// ---------------------------------------------------------------------------
__global__ __launch_bounds__(256) void flash_attn(
    const ushort* __restrict__ Q, const ushort* __restrict__ Kb,
    const ushort* __restrict__ Vt, ushort* __restrict__ AO)
{
  __shared__ __align__(16) ushort Kt[64 * 128];    // [kn][d] swizzled
  __shared__ __align__(16) ushort Vs[128 * 64];    // [d][kn] swizzled
  __shared__ __align__(16) ushort Ps[4][32 * 64];  // per-wave P [q][kn] swizzled

  const int tid  = threadIdx.x;
  const int wave = tid >> 6;
  const int lane = tid & 63;
  const int quad = lane >> 4;
  const int l16  = lane & 15;
  const int h  = blockIdx.y;
  const int q0 = blockIdx.x * 128 + wave * 32;
  const float scale = 0.08838834764831845f;  // 1/sqrt(128)

  bf16x8 aq[2][4];
#pragma unroll
  for (int m = 0; m < 2; m++)
#pragma unroll
    for (int kt = 0; kt < 4; kt++)
      aq[m][kt] = *(const bf16x8*)(Q + (size_t)(q0 + m * 16 + l16) * 4096 +
                                   h * 128 + kt * 32 + quad * 8);

  f32x4 Oacc[2][8];
#pragma unroll
  for (int m = 0; m < 2; m++)
#pragma unroll
    for (int dt = 0; dt < 8; dt++) Oacc[m][dt] = {0.f, 0.f, 0.f, 0.f};
  float m_i[2][4], l_i[2][4];
#pragma unroll
  for (int m = 0; m < 2; m++)
#pragma unroll
    for (int r = 0; r < 4; r++) { m_i[m][r] = -1e30f; l_i[m][r] = 0.f; }

  ushort* myP = &Ps[wave][0];

  for (int kv = 0; kv < 2048; kv += 64) {
    __syncthreads();
#pragma unroll
    for (int it = 0; it < 4; it++) {
      int i  = tid + it * 256;      // 0..1023
      int kr = i >> 4, kg = i & 15; // K: row 0..63, 16 groups
      *(uint4*)(Kt + kr * 128 + ((kg ^ (kr & 15)) * 8)) =
          *(const uint4*)(Kb + (size_t)(kv + kr) * 4096 + h * 128 + kg * 8);
      int vr = i >> 3, vg = i & 7;  // V: row 0..127, 8 groups
      *(uint4*)(Vs + vr * 64 + ((vg ^ (vr & 7)) * 8)) =
          *(const uint4*)(Vt + (size_t)(h * 128 + vr) * 2048 + kv + vg * 8);
    }
    __syncthreads();

    // S = Q K^T
    f32x4 sA[2][4];
#pragma unroll
    for (int m = 0; m < 2; m++)
#pragma unroll
      for (int nt = 0; nt < 4; nt++) sA[m][nt] = {0.f, 0.f, 0.f, 0.f};
#pragma unroll
    for (int nt = 0; nt < 4; nt++) {
      int row = nt * 16 + l16;
#pragma unroll
      for (int kt = 0; kt < 4; kt++) {
        int g = kt * 4 + quad;
        bf16x8 bk = *(const bf16x8*)(Kt + row * 128 + ((g ^ (row & 15)) * 8));
        sA[0][nt] = __builtin_amdgcn_mfma_f32_16x16x32_bf16(aq[0][kt], bk, sA[0][nt], 0, 0, 0);
        sA[1][nt] = __builtin_amdgcn_mfma_f32_16x16x32_bf16(aq[1][kt], bk, sA[1][nt], 0, 0, 0);
      }
    }

#pragma unroll
    for (int m = 0; m < 2; m++) {
      float tmax[4];
#pragma unroll
      for (int r = 0; r < 4; r++) {
        float mx = sA[m][0][r];
#pragma unroll
        for (int nt = 1; nt < 4; nt++) mx = fmaxf(mx, sA[m][nt][r]);
        tmax[r] = mx;
      }
#pragma unroll
      for (int msk = 1; msk < 16; msk <<= 1)
#pragma unroll
        for (int r = 0; r < 4; r++)
          tmax[r] = fmaxf(tmax[r], __shfl_xor(tmax[r], msk));

      float alpha[4];
#pragma unroll
      for (int r = 0; r < 4; r++) {
        float mn = fmaxf(m_i[m][r], tmax[r] * scale);
        alpha[r] = __expf(m_i[m][r] - mn);
        m_i[m][r] = mn;
      }
      float rsum[4] = {0.f, 0.f, 0.f, 0.f};
#pragma unroll
      for (int nt = 0; nt < 4; nt++)
#pragma unroll
        for (int r = 0; r < 4; r++) {
          float p = __expf(sA[m][nt][r] * scale - m_i[m][r]);
          sA[m][nt][r] = p;
          rsum[r] += p;
        }
#pragma unroll
      for (int msk = 1; msk < 16; msk <<= 1)
#pragma unroll
        for (int r = 0; r < 4; r++) rsum[r] += __shfl_xor(rsum[r], msk);
#pragma unroll
      for (int r = 0; r < 4; r++) l_i[m][r] = l_i[m][r] * alpha[r] + rsum[r];

      // P -> LDS (bf16, swizzled)
#pragma unroll
      for (int nt = 0; nt < 4; nt++)
#pragma unroll
        for (int r = 0; r < 4; r++) {
          int row = m * 16 + quad * 4 + r;
          int col = nt * 16 + l16;
          myP[row * 64 + (((col >> 3) ^ (row & 7)) * 8) + (col & 7)] =
              f2bf(sA[m][nt][r]);
        }

      // rescale O
#pragma unroll
      for (int dt = 0; dt < 8; dt++)
#pragma unroll
        for (int r = 0; r < 4; r++) Oacc[m][dt][r] *= alpha[r];
    }

    // O += P V
#pragma unroll
    for (int kt = 0; kt < 2; kt++) {
      int g = kt * 4 + quad;
      bf16x8 ap0 = *(const bf16x8*)(myP + (l16) * 64 + ((g ^ (l16 & 7)) * 8));
      bf16x8 ap1 = *(const bf16x8*)(myP + (16 + l16) * 64 + ((g ^ (l16 & 7)) * 8));
#pragma unroll
      for (int dt = 0; dt < 8; dt++) {
        int vrow = dt * 16 + l16;
        bf16x8 bv = *(const bf16x8*)(Vs + vrow * 64 + ((g ^ (vrow & 7)) * 8));
        Oacc[0][dt] = __builtin_amdgcn_mfma_f32_16x16x32_bf16(ap0, bv, Oacc[0][dt], 0, 0, 0);
        Oacc[1][dt] = __builtin_amdgcn_mfma_f32_16x16x32_bf16(ap1, bv, Oacc[1][dt], 0, 0, 0);
      }
    }
  }

#pragma unroll
  for (int m = 0; m < 2; m++)
#pragma unroll
    for (int dt = 0; dt < 8; dt++)
#pragma unroll
      for (int r = 0; r < 4; r++) {
        int row = q0 + m * 16 + quad * 4 + r;
        int col = h * 128 + dt * 16 + l16;
        AO[(size_t)row * 4096 + col] = f2bf(Oacc[m][dt][r] / l_i[m][r]);
      }
}

// ---------------------------------------------------------------------------
extern "C" void kernel_launch(void* const* d_in, const int* in_sizes, int n_in,
                              void* d_out, int out_size, void* d_ws, size_t ws_size,
                              hipStream_t stream)
{
  const float* hidden  = (const float*)d_in[0];
  const float* Wq      = (const float*)d_in[2];
  const float* Wk      = (const float*)d_in[3];
  const float* Wv      = (const float*)d_in[4];
  const float* Wo      = (const float*)d_in[5];
  const float* latents = (const float*)d_in[6];
  float* out = (float*)d_out;

  const size_t SB = (size_t)2048 * 4096 * 2;  // 16 MiB: one [2048,4096] bf16
  char* w = (char*)d_ws;

  dim3 gemm_grid(32, 16);  // N/128, M/128
  const int n8_act = 2048 * 4096 / 8;
  const int n8_wt  = 4096 * 4096 / 8;

  if (ws_size >= 13 * SB) {
    // fast path: pre-convert everything to bf16, async-staging GEMMs
    ushort* hb  = (ushort*)(w);
    ushort* lb  = (ushort*)(w + 1 * SB);
    ushort* wqb = (ushort*)(w + 2 * SB);   // 2 SB each
    ushort* wkb = (ushort*)(w + 4 * SB);
    ushort* wvb = (ushort*)(w + 6 * SB);
    ushort* wob = (ushort*)(w + 8 * SB);
    ushort* Qb  = (ushort*)(w + 10 * SB);
    ushort* Kbf = (ushort*)(w + 11 * SB);
    ushort* Vtb = (ushort*)(w + 12 * SB);
    ushort* AOb = wqb;  // reuse after Q-GEMM

    cvt_bf16<<<n8_act / 256, 256, 0, stream>>>(hidden,  hb,  n8_act);
    cvt_bf16<<<n8_act / 256, 256, 0, stream>>>(latents, lb,  n8_act);
    cvt_bf16<<<n8_wt / 256, 256, 0, stream>>>(Wq, wqb, n8_wt);
    cvt_bf16<<<n8_wt / 256, 256, 0, stream>>>(Wk, wkb, n8_wt);
    cvt_bf16<<<n8_wt / 256, 256, 0, stream>>>(Wv, wvb, n8_wt);
    cvt_bf16<<<n8_wt / 256, 256, 0, stream>>>(Wo, wob, n8_wt);

    gemm_bt_async<false, ushort><<<gemm_grid, 256, 0, stream>>>(lb, wqb, Qb, 2048, 4096, 4096, 4096);
    gemm_bt_async<false, ushort><<<gemm_grid, 256, 0, stream>>>(hb, wkb, Kbf, 2048, 4096, 4096, 4096);
    gemm_bt_async<true,  ushort><<<gemm_grid, 256, 0, stream>>>(hb, wvb, Vtb, 2048, 4096, 4096, 2048);
    rope_kernel<<<(2048 * 32 * 64) / 256, 256, 0, stream>>>(Kbf);
    flash_attn<<<dim3(16, 32), 256, 0, stream>>>(Qb, Kbf, Vtb, AOb);
    gemm_bt_async<false, float><<<gemm_grid, 256, 0, stream>>>(AOb, wob, out, 2048, 4096, 4096, 4096);
  } else {
    // fallback: round-1 mixed-dtype GEMMs, 4 bf16 ws buffers
    ushort* Qb  = (ushort*)(w);
    ushort* Kbf = (ushort*)(w + 1 * SB);
    ushort* Vtb = (ushort*)(w + 2 * SB);
    ushort* AOb = (ushort*)(w + 3 * SB);

    gemm_bt<false><<<gemm_grid, 256, 0, stream>>>(latents, Wq, Qb, 2048, 4096, 4096, 4096);
    gemm_bt<false><<<gemm_grid, 256, 0, stream>>>(hidden, Wk, Kbf, 2048, 4096, 4096, 4096);
    gemm_bt<true><<<gemm_grid, 256, 0, stream>>>(hidden, Wv, Vtb, 2048, 4096, 4096, 2048);
    rope_kernel<<<(2048 * 32 * 64) / 256, 256, 0, stream>>>(Kbf);
    flash_attn<<<dim3(16, 32), 256, 0, stream>>>(Qb, Kbf, Vtb, AOb);
    gemm_bt<false><<<gemm_grid, 256, 0, stream>>>(AOb, Wo, out, 2048, 4096, 4096, 4096);
  }
}

// Round 4
// 1031.452 us; speedup vs baseline: 1.1008x; 1.1008x over previous
//
#include <hip/hip_runtime.h>
#include <cstdint>
#include <type_traits>

typedef short bf16x8 __attribute__((ext_vector_type(8)));
typedef float f32x4 __attribute__((ext_vector_type(4)));

__device__ __forceinline__ ushort f2bf(float f) {
  union { float f; uint32_t u; } v; v.f = f;
  return (ushort)((v.u + 0x7fffu + ((v.u >> 16) & 1u)) >> 16);
}
__device__ __forceinline__ float bf2f(ushort u) {
  union { uint32_t u; float f; } v; v.u = ((uint32_t)u) << 16;
  return v.f;
}
__device__ __forceinline__ uint32_t pkbf(float x, float y) {
  uint32_t ux = (__float_as_uint(x) + 0x8000u) >> 16;
  uint32_t uy = (__float_as_uint(y) + 0x8000u) & 0xffff0000u;
  return ux | uy;
}

// async global->LDS, 16B per lane; LDS base must be wave-uniform
__device__ __forceinline__ void gld16(const void* g, void* l) {
  __builtin_amdgcn_global_load_lds(
      (__attribute__((address_space(1))) void*)(g),
      (__attribute__((address_space(3))) void*)(l), 16, 0, 0);
}

__device__ __forceinline__ uint4 ld8(const ushort* p) { return *(const uint4*)p; }
__device__ __forceinline__ uint4 ld8(const float* p) {
  float4 a = *(const float4*)p;
  float4 b = *(const float4*)(p + 4);
  uint4 r;
  r.x = pkbf(a.x, a.y); r.y = pkbf(a.z, a.w);
  r.z = pkbf(b.x, b.y); r.w = pkbf(b.z, b.w);
  return r;
}

// ---------------------------------------------------------------------------
// fp32 -> bf16 bulk convert: 8 elements/thread
// ---------------------------------------------------------------------------
__global__ __launch_bounds__(256) void cvt_bf16(
    const float* __restrict__ src, ushort* __restrict__ dst, int n8)
{
  int i = blockIdx.x * 256 + threadIdx.x;
  if (i >= n8) return;
  const float4* s = (const float4*)src;
  float4 a = s[2 * i], b = s[2 * i + 1];
  uint4 r;
  r.x = pkbf(a.x, a.y); r.y = pkbf(a.z, a.w);
  r.z = pkbf(b.x, b.y); r.w = pkbf(b.z, b.w);
  ((uint4*)dst)[i] = r;
}

// ---------------------------------------------------------------------------
// Fused QKV GEMM (bf16): one dispatch, 1536 blocks.
//   x in [0,64):  C = hidden * [Wk;Wv]^T  -> route to Kbf (n<4096) or Vtb^T
//   x in [64,96): C = latents * Wq^T      -> Qb
// 128x128 tile, BK=32, global_load_lds staging, 4 waves 2x2, 4x4 MFMA.
// ---------------------------------------------------------------------------
__global__ __launch_bounds__(256) void gemm_qkv(
    const ushort* __restrict__ hb, const ushort* __restrict__ lb,
    const ushort* __restrict__ wkv, const ushort* __restrict__ wq,
    ushort* __restrict__ Kbf, ushort* __restrict__ Vtb, ushort* __restrict__ Qb)
{
  __shared__ __align__(16) ushort As[128 * 32];
  __shared__ __align__(16) ushort Bs[128 * 32];

  const int tid  = threadIdx.x;
  const int wave = tid >> 6;
  const int lane = tid & 63;
  const int quad = lane >> 4;
  const int l16  = lane & 15;
  const int xt = blockIdx.x;
  const int m0 = blockIdx.y * 128;
  const int K  = 4096;

  const ushort* A; const ushort* B; int n0;
  if (xt < 64) { A = hb; B = wkv; n0 = xt * 128; }
  else         { A = lb; B = wq;  n0 = (xt - 64) * 128; }

  const int wm = (wave & 1) * 64;
  const int wn = (wave >> 1) * 64;
  const int srow = lane >> 2;
  const int scol = (lane & 3) * 8;
  const ushort* ga0 = A + (size_t)(m0 + 32 * wave + srow) * K + scol;
  const ushort* ga1 = ga0 + (size_t)16 * K;
  const ushort* gb0 = B + (size_t)(n0 + 32 * wave + srow) * K + scol;
  const ushort* gb1 = gb0 + (size_t)16 * K;
  ushort* la0 = As + (2 * wave) * 512;
  ushort* la1 = As + (2 * wave + 1) * 512;
  ushort* lb0 = Bs + (2 * wave) * 512;
  ushort* lb1 = Bs + (2 * wave + 1) * 512;

  f32x4 acc[4][4];
#pragma unroll
  for (int i = 0; i < 4; i++)
#pragma unroll
    for (int j = 0; j < 4; j++) acc[i][j] = {0.f, 0.f, 0.f, 0.f};

  for (int k0 = 0; k0 < K; k0 += 32) {
    __syncthreads();
    gld16(ga0 + k0, la0);
    gld16(ga1 + k0, la1);
    gld16(gb0 + k0, lb0);
    gld16(gb1 + k0, lb1);
    __syncthreads();

    bf16x8 af[4], bfr[4];
#pragma unroll
    for (int i = 0; i < 4; i++) {
      af[i]  = *(const bf16x8*)(As + (wm + i * 16 + l16) * 32 + quad * 8);
      bfr[i] = *(const bf16x8*)(Bs + (wn + i * 16 + l16) * 32 + quad * 8);
    }
#pragma unroll
    for (int im = 0; im < 4; im++)
#pragma unroll
      for (int in = 0; in < 4; in++)
        acc[im][in] = __builtin_amdgcn_mfma_f32_16x16x32_bf16(
            af[im], bfr[in], acc[im][in], 0, 0, 0);
  }

  // route: 0 = K, 1 = V (transposed), 2 = Q
  int route = (xt >= 64) ? 2 : (n0 >= 4096 ? 1 : 0);
#pragma unroll
  for (int im = 0; im < 4; im++)
#pragma unroll
    for (int in = 0; in < 4; in++)
#pragma unroll
      for (int r = 0; r < 4; r++) {
        int row = m0 + wm + im * 16 + quad * 4 + r;
        int col = n0 + wn + in * 16 + l16;
        ushort val = f2bf(acc[im][in][r]);
        if (route == 0)      Kbf[(size_t)row * 4096 + col] = val;
        else if (route == 1) Vtb[(size_t)(col - 4096) * 2048 + row] = val;
        else                 Qb[(size_t)row * 4096 + col] = val;
      }
}

// ---------------------------------------------------------------------------
// Split-K GEMM for out = AO * Wo^T : blockIdx.z selects K-half; fp32 partials.
// ---------------------------------------------------------------------------
__global__ __launch_bounds__(256) void gemm_splitk(
    const ushort* __restrict__ A, const ushort* __restrict__ B,
    float* __restrict__ P)  // P[z][2048][4096]
{
  __shared__ __align__(16) ushort As[128 * 32];
  __shared__ __align__(16) ushort Bs[128 * 32];

  const int tid  = threadIdx.x;
  const int wave = tid >> 6;
  const int lane = tid & 63;
  const int quad = lane >> 4;
  const int l16  = lane & 15;
  const int m0 = blockIdx.y * 128;
  const int n0 = blockIdx.x * 128;
  const int K  = 4096;
  const int kb = blockIdx.z * 2048;

  const int wm = (wave & 1) * 64;
  const int wn = (wave >> 1) * 64;
  const int srow = lane >> 2;
  const int scol = (lane & 3) * 8;
  const ushort* ga0 = A + (size_t)(m0 + 32 * wave + srow) * K + scol + kb;
  const ushort* ga1 = ga0 + (size_t)16 * K;
  const ushort* gb0 = B + (size_t)(n0 + 32 * wave + srow) * K + scol + kb;
  const ushort* gb1 = gb0 + (size_t)16 * K;
  ushort* la0 = As + (2 * wave) * 512;
  ushort* la1 = As + (2 * wave + 1) * 512;
  ushort* lb0 = Bs + (2 * wave) * 512;
  ushort* lb1 = Bs + (2 * wave + 1) * 512;

  f32x4 acc[4][4];
#pragma unroll
  for (int i = 0; i < 4; i++)
#pragma unroll
    for (int j = 0; j < 4; j++) acc[i][j] = {0.f, 0.f, 0.f, 0.f};

  for (int k0 = 0; k0 < 2048; k0 += 32) {
    __syncthreads();
    gld16(ga0 + k0, la0);
    gld16(ga1 + k0, la1);
    gld16(gb0 + k0, lb0);
    gld16(gb1 + k0, lb1);
    __syncthreads();

    bf16x8 af[4], bfr[4];
#pragma unroll
    for (int i = 0; i < 4; i++) {
      af[i]  = *(const bf16x8*)(As + (wm + i * 16 + l16) * 32 + quad * 8);
      bfr[i] = *(const bf16x8*)(Bs + (wn + i * 16 + l16) * 32 + quad * 8);
    }
#pragma unroll
    for (int im = 0; im < 4; im++)
#pragma unroll
      for (int in = 0; in < 4; in++)
        acc[im][in] = __builtin_amdgcn_mfma_f32_16x16x32_bf16(
            af[im], bfr[in], acc[im][in], 0, 0, 0);
  }

  float* myP = P + (size_t)blockIdx.z * 2048 * 4096;
#pragma unroll
  for (int im = 0; im < 4; im++)
#pragma unroll
    for (int in = 0; in < 4; in++)
#pragma unroll
      for (int r = 0; r < 4; r++) {
        int row = m0 + wm + im * 16 + quad * 4 + r;
        int col = n0 + wn + in * 16 + l16;
        myP[(size_t)row * 4096 + col] = acc[im][in][r];
      }
}

__global__ __launch_bounds__(256) void reduce2(
    const float* __restrict__ P, float* __restrict__ out, int n4)
{
  int i = blockIdx.x * 256 + threadIdx.x;
  if (i >= n4) return;
  const float4* p0 = (const float4*)P;
  const float4* p1 = (const float4*)(P + (size_t)2048 * 4096);
  float4 a = p0[i], b = p1[i];
  float4 r; r.x = a.x + b.x; r.y = a.y + b.y; r.z = a.z + b.z; r.w = a.w + b.w;
  ((float4*)out)[i] = r;
}

// ---------------------------------------------------------------------------
// FALLBACK GEMM (mixed fp32/bf16 inputs, VGPR staging)
// ---------------------------------------------------------------------------
template <bool TRANSC, typename TA, typename TB, typename TC>
__global__ __launch_bounds__(256) void gemm_bt(
    const TA* __restrict__ A, const TB* __restrict__ B,
    TC* __restrict__ C, int M, int N, int K, int ldc)
{
  __shared__ __align__(16) ushort As[128 * 32];
  __shared__ __align__(16) ushort Bs[128 * 32];

  const int tid  = threadIdx.x;
  const int wave = tid >> 6;
  const int lane = tid & 63;
  const int quad = lane >> 4;
  const int l16  = lane & 15;
  const int m0 = blockIdx.y * 128;
  const int n0 = blockIdx.x * 128;
  const int wm = (wave & 1) * 64;
  const int wn = (wave >> 1) * 64;
  const int r0 = tid >> 2;
  const int c0 = (tid & 3) * 8;

  f32x4 acc[4][4];
#pragma unroll
  for (int i = 0; i < 4; i++)
#pragma unroll
    for (int j = 0; j < 4; j++) acc[i][j] = {0.f, 0.f, 0.f, 0.f};

  const TA* aptr = A + (size_t)(m0 + r0) * K + c0;
  const TB* bptr = B + (size_t)(n0 + r0) * K + c0;

  for (int k0 = 0; k0 < K; k0 += 32) {
    uint4 av0 = ld8(aptr + k0);
    uint4 av1 = ld8(aptr + (size_t)64 * K + k0);
    uint4 bv0 = ld8(bptr + k0);
    uint4 bv1 = ld8(bptr + (size_t)64 * K + k0);
    __syncthreads();
    *(uint4*)(As + r0 * 32 + c0)        = av0;
    *(uint4*)(As + (r0 + 64) * 32 + c0) = av1;
    *(uint4*)(Bs + r0 * 32 + c0)        = bv0;
    *(uint4*)(Bs + (r0 + 64) * 32 + c0) = bv1;
    __syncthreads();

    bf16x8 af[4], bfr[4];
#pragma unroll
    for (int i = 0; i < 4; i++) {
      af[i]  = *(const bf16x8*)(As + (wm + i * 16 + l16) * 32 + quad * 8);
      bfr[i] = *(const bf16x8*)(Bs + (wn + i * 16 + l16) * 32 + quad * 8);
    }
#pragma unroll
    for (int im = 0; im < 4; im++)
#pragma unroll
      for (int in = 0; in < 4; in++)
        acc[im][in] = __builtin_amdgcn_mfma_f32_16x16x32_bf16(
            af[im], bfr[in], acc[im][in], 0, 0, 0);
  }

#pragma unroll
  for (int im = 0; im < 4; im++)
#pragma unroll
    for (int in = 0; in < 4; in++)
#pragma unroll
      for (int r = 0; r < 4; r++) {
        int row = m0 + wm + im * 16 + quad * 4 + r;
        int col = n0 + wn + in * 16 + l16;
        float fv = acc[im][in][r];
        TC val;
        if constexpr (std::is_same<TC, ushort>::value) val = f2bf(fv);
        else                                           val = fv;
        if (TRANSC) C[(size_t)col * ldc + row] = val;
        else        C[(size_t)row * ldc + col] = val;
      }
}

// ---------------------------------------------------------------------------
// RoPE on K (bf16) in place
// ---------------------------------------------------------------------------
__global__ __launch_bounds__(256) void rope_kernel(ushort* __restrict__ Kb)
{
  int idx = blockIdx.x * 256 + threadIdx.x;
  int j  = idx & 63;
  int hs = idx >> 6;
  int s  = hs >> 5;
  float freq = expf(-0.14391156f * (float)j);
  float ang  = (float)s * freq;
  float sn, c;
  sincosf(ang, &sn, &c);
  size_t base = (size_t)hs * 128 + j;
  float k1 = bf2f(Kb[base]);
  float k2 = bf2f(Kb[base + 64]);
  Kb[base]      = f2bf(k1 * c - k2 * sn);
  Kb[base + 64] = f2bf(k2 * c + k1 * sn);
}

// ---------------------------------------------------------------------------
// Flash attention (round-2 proven version): block = 1 head x 64 q rows,
// 128-key tiles, 80KB LDS, grid 32x32 = 1024 blocks.
// ---------------------------------------------------------------------------
__global__ __launch_bounds__(256) void flash_attn(
    const ushort* __restrict__ Q, const ushort* __restrict__ Kb,
    const ushort* __restrict__ Vt, ushort* __restrict__ AO)
{
  __shared__ __align__(16) ushort Kt[128 * 128];
  __shared__ __align__(16) ushort Vs[128 * 128];
  __shared__ __align__(16) ushort Ps[4][16 * 128];

  const int tid  = threadIdx.x;
  const int wave = tid >> 6;
  const int lane = tid & 63;
  const int quad = lane >> 4;
  const int l16  = lane & 15;
  const int h  = blockIdx.y;
  const int q0 = blockIdx.x * 64 + wave * 16;
  const float scale = 0.08838834764831845f;

  bf16x8 aq[4];
#pragma unroll
  for (int kt = 0; kt < 4; kt++)
    aq[kt] = *(const bf16x8*)(Q + (size_t)(q0 + l16) * 4096 + h * 128 + kt * 32 + quad * 8);

  f32x4 Oacc[8];
#pragma unroll
  for (int dt = 0; dt < 8; dt++) Oacc[dt] = {0.f, 0.f, 0.f, 0.f};
  float m_i[4], l_i[4];
#pragma unroll
  for (int r = 0; r < 4; r++) { m_i[r] = -1e30f; l_i[r] = 0.f; }

  ushort* myP = &Ps[wave][0];

  for (int kv = 0; kv < 2048; kv += 128) {
    __syncthreads();
#pragma unroll
    for (int it = 0; it < 8; it++) {
      int i   = tid + it * 256;
      int row = i >> 4;
      int g   = i & 15;
      int sw  = (g ^ (row & 15)) * 8;
      *(uint4*)(Kt + row * 128 + sw) =
          *(const uint4*)(Kb + (size_t)(kv + row) * 4096 + h * 128 + g * 8);
      *(uint4*)(Vs + row * 128 + sw) =
          *(const uint4*)(Vt + (size_t)(h * 128 + row) * 2048 + kv + g * 8);
    }
    __syncthreads();

    f32x4 sA[8];
#pragma unroll
    for (int nt = 0; nt < 8; nt++) sA[nt] = {0.f, 0.f, 0.f, 0.f};
#pragma unroll
    for (int nt = 0; nt < 8; nt++) {
      int row = nt * 16 + l16;
#pragma unroll
      for (int kt = 0; kt < 4; kt++) {
        int g = kt * 4 + quad;
        bf16x8 bk = *(const bf16x8*)(Kt + row * 128 + ((g ^ (row & 15)) * 8));
        sA[nt] = __builtin_amdgcn_mfma_f32_16x16x32_bf16(aq[kt], bk, sA[nt], 0, 0, 0);
      }
    }

    float tmax[4];
#pragma unroll
    for (int r = 0; r < 4; r++) {
      float m = sA[0][r];
#pragma unroll
      for (int nt = 1; nt < 8; nt++) m = fmaxf(m, sA[nt][r]);
      tmax[r] = m;
    }
#pragma unroll
    for (int msk = 1; msk < 16; msk <<= 1)
#pragma unroll
      for (int r = 0; r < 4; r++)
        tmax[r] = fmaxf(tmax[r], __shfl_xor(tmax[r], msk));

    float alpha[4];
#pragma unroll
    for (int r = 0; r < 4; r++) {
      float mn = fmaxf(m_i[r], tmax[r] * scale);
      alpha[r] = __expf(m_i[r] - mn);
      m_i[r] = mn;
    }
    float rsum[4] = {0.f, 0.f, 0.f, 0.f};
#pragma unroll
    for (int nt = 0; nt < 8; nt++)
#pragma unroll
      for (int r = 0; r < 4; r++) {
        float p = __expf(sA[nt][r] * scale - m_i[r]);
        sA[nt][r] = p;
        rsum[r] += p;
      }
#pragma unroll
    for (int msk = 1; msk < 16; msk <<= 1)
#pragma unroll
      for (int r = 0; r < 4; r++) rsum[r] += __shfl_xor(rsum[r], msk);
#pragma unroll
    for (int r = 0; r < 4; r++) l_i[r] = l_i[r] * alpha[r] + rsum[r];

#pragma unroll
    for (int nt = 0; nt < 8; nt++)
#pragma unroll
      for (int r = 0; r < 4; r++) {
        int row = quad * 4 + r;
        int col = nt * 16 + l16;
        myP[row * 128 + (((col >> 3) ^ row) * 8) + (col & 7)] = f2bf(sA[nt][r]);
      }

#pragma unroll
    for (int dt = 0; dt < 8; dt++)
#pragma unroll
      for (int r = 0; r < 4; r++) Oacc[dt][r] *= alpha[r];

#pragma unroll
    for (int kt = 0; kt < 4; kt++) {
      int g = kt * 4 + quad;
      bf16x8 ap = *(const bf16x8*)(myP + l16 * 128 + ((g ^ l16) * 8));
#pragma unroll
      for (int dt = 0; dt < 8; dt++) {
        int vrow = dt * 16 + l16;
        bf16x8 bv = *(const bf16x8*)(Vs + vrow * 128 + ((g ^ (vrow & 15)) * 8));
        Oacc[dt] = __builtin_amdgcn_mfma_f32_16x16x32_bf16(ap, bv, Oacc[dt], 0, 0, 0);
      }
    }
  }

#pragma unroll
  for (int dt = 0; dt < 8; dt++)
#pragma unroll
    for (int r = 0; r < 4; r++) {
      int row = q0 + quad * 4 + r;
      int col = h * 128 + dt * 16 + l16;
      AO[(size_t)row * 4096 + col] = f2bf(Oacc[dt][r] / l_i[r]);
    }
}

// ---------------------------------------------------------------------------
extern "C" void kernel_launch(void* const* d_in, const int* in_sizes, int n_in,
                              void* d_out, int out_size, void* d_ws, size_t ws_size,
                              hipStream_t stream)
{
  const float* hidden  = (const float*)d_in[0];
  const float* Wq      = (const float*)d_in[2];
  const float* Wk      = (const float*)d_in[3];
  const float* Wv      = (const float*)d_in[4];
  const float* Wo      = (const float*)d_in[5];
  const float* latents = (const float*)d_in[6];
  float* out = (float*)d_out;

  const size_t SB = (size_t)2048 * 4096 * 2;  // 16 MiB
  char* w = (char*)d_ws;
  const int n8_act = 2048 * 4096 / 8;
  const int n8_wt  = 4096 * 4096 / 8;

  if (ws_size >= 13 * SB) {
    ushort* hb  = (ushort*)(w);
    ushort* lb  = (ushort*)(w + 1 * SB);
    ushort* wqb = (ushort*)(w + 2 * SB);   // 2 SB
    ushort* wkv = (ushort*)(w + 4 * SB);   // 4 SB: [Wk;Wv] stacked [8192,4096]
    ushort* wob = (ushort*)(w + 8 * SB);   // 2 SB
    ushort* Qb  = (ushort*)(w + 10 * SB);
    ushort* Kbf = (ushort*)(w + 11 * SB);
    ushort* Vtb = (ushort*)(w + 12 * SB);
    ushort* AOb = wqb;                      // reuse after QKV GEMM
    float*  Pp  = (float*)(w + 4 * SB);     // 64MB partials, reuse wkv region

    cvt_bf16<<<n8_act / 256, 256, 0, stream>>>(hidden,  hb,  n8_act);
    cvt_bf16<<<n8_act / 256, 256, 0, stream>>>(latents, lb,  n8_act);
    cvt_bf16<<<n8_wt / 256, 256, 0, stream>>>(Wq, wqb, n8_wt);
    cvt_bf16<<<n8_wt / 256, 256, 0, stream>>>(Wk, wkv, n8_wt);
    cvt_bf16<<<n8_wt / 256, 256, 0, stream>>>(Wv, wkv + (size_t)4096 * 4096, n8_wt);
    cvt_bf16<<<n8_wt / 256, 256, 0, stream>>>(Wo, wob, n8_wt);

    gemm_qkv<<<dim3(96, 16), 256, 0, stream>>>(hb, lb, wkv, wqb, Kbf, Vtb, Qb);
    rope_kernel<<<(2048 * 32 * 64) / 256, 256, 0, stream>>>(Kbf);
    flash_attn<<<dim3(32, 32), 256, 0, stream>>>(Qb, Kbf, Vtb, AOb);
    gemm_splitk<<<dim3(32, 16, 2), 256, 0, stream>>>(AOb, wob, Pp);
    reduce2<<<(2048 * 4096 / 4 + 255) / 256, 256, 0, stream>>>(Pp, out, 2048 * 4096 / 4);
  } else {
    ushort* Qb  = (ushort*)(w);
    ushort* Kbf = (ushort*)(w + 1 * SB);
    ushort* Vtb = (ushort*)(w + 2 * SB);
    ushort* AOb = (ushort*)(w + 3 * SB);

    gemm_bt<false><<<dim3(32, 16), 256, 0, stream>>>(latents, Wq, Qb, 2048, 4096, 4096, 4096);
    gemm_bt<false><<<dim3(32, 16), 256, 0, stream>>>(hidden, Wk, Kbf, 2048, 4096, 4096, 4096);
    gemm_bt<true><<<dim3(32, 16), 256, 0, stream>>>(hidden, Wv, Vtb, 2048, 4096, 4096, 2048);
    rope_kernel<<<(2048 * 32 * 64) / 256, 256, 0, stream>>>(Kbf);
    flash_attn<<<dim3(32, 32), 256, 0, stream>>>(Qb, Kbf, Vtb, AOb);
    gemm_bt<false><<<dim3(32, 16), 256, 0, stream>>>(AOb, Wo, out, 2048, 4096, 4096, 4096);
  }
}